// Round 2
// baseline (225.548 us; speedup 1.0000x reference)
//
#include <hip/hip_runtime.h>
#include <hip/hip_fp16.h>

#define R_ 3
#define D_ 7            // 2R+1
#define W_ 49
#define N_ 128
#define K_ 131
#define C_ 21
#define B_ 2
#define NN (N_ * N_)
#define TI_ 8                   // tile rows
#define TJ_ 16                  // tile cols
#define PROWS (TI_ + 2 * R_)    // 14
#define PCOLS (TJ_ + 2 * R_)    // 22
#define PSTR 24                 // LDS row stride (float2 pairs)
#define NELEM (PROWS * PCOLS)   // 308 staged elements
#define LDSP (PROWS * PSTR + 8) // 344 pairs (spare write slot at 340)
#define KC 8                    // k-chunks per tile (131 = 3x17 + 5x16)

typedef __fp16 h2 __attribute__((ext_vector_type(2)));

// Affinity: per-pixel 7x7 window softmax per channel, weighted by cp[k].
// exp(|c-n|) = max(Ec*EnInv, En*EcInv), (E,Einv) float2 pairs staged per
// element (E = exp2(f*mask*log2e)). Lane pairs (2t,2t+1) share a pixel;
// h=tid&1 owns columns v=2s+h (s=0..3). The h=1,s=3 tap is the phantom v=7:
// it reads a REAL staged element, killed explicitly with ph.
//
// R2 changes vs the proven 73.7us R0 version (numerics identical):
//  * VGPR=32 was starving the tap loop: 28 ds_read results had ~4 spare
//    regs -> serialized waitcnt per 1-2 loads, per-SIMD issue ~25%.
//    Now: per-u batch of 4 float2 loads with 1-row lookahead in registers,
//    __launch_bounds__(256,8) caps at 64 VGPR (no occupancy cliff).
//  * Double-buffered LDS staging -> ONE barrier per k (was two).
//  * Global prefetch issued 2 k's ahead of use.
//  * Balanced k-chunks: 3x17 + 5x16 (was 7x17 + 12) -> less tail imbalance.
__global__ __launch_bounds__(256, 8) void rwn_affinity(
    const float* __restrict__ feats,   // [B,K,N,N]
    const int*   __restrict__ mask,    // [B,N,N]
    const float* __restrict__ cp,      // [K]
    float* __restrict__ Aout)          // [B,W,NN] (pre-zeroed)
{
    __shared__ float2 patch2[2][LDSP];

    const int tile = blockIdx.x;           // 0..127 (16x8 tiles of 8x16)
    const int kc   = blockIdx.y;
    const int b    = blockIdx.z;
    const int tr = tile >> 3, tc = tile & 7;
    const int ti0 = tr * TI_, tj0 = tc * TJ_;

    const int tid = threadIdx.x;
    const int pix = tid >> 1;              // 0..127
    const int h   = tid & 1;               // column-parity owner
    const int ti = pix >> 4;               // 0..7
    const int tj = pix & 15;               // 0..15
    const int gi = ti0 + ti, gj = tj0 + tj;

    // ---- hoisted staging setup: thread owns elements tid and 256+tid ----
    const float LOG2E = 1.4426950408889634f;
    int   soff[2];      // clamped global offset
    float swt[2];       // in-bounds * mask * log2e
    float ozw[2];       // 0 for OOB (store zero pair), 1 otherwise
    int   slds[2];      // pair index in LDS
    #pragma unroll
    for (int r = 0; r < 2; ++r) {
        int e = tid + r * 256;
        bool act = (e < NELEM);
        int pr = e / PCOLS, pc = e - pr * PCOLS;
        int mi = ti0 + pr - R_, mj = tj0 + pc - R_;
        bool inb = act && mi >= 0 && mi < N_ && mj >= 0 && mj < N_;
        int cmi = mi < 0 ? 0 : (mi > N_ - 1 ? N_ - 1 : mi);
        int cmj = mj < 0 ? 0 : (mj > N_ - 1 ? N_ - 1 : mj);
        soff[r] = cmi * N_ + cmj;
        swt[r]  = inb ? ((float)mask[b * NN + soff[r]] * LOG2E) : 0.f;
        ozw[r]  = inb ? 1.f : 0.f;
        slds[r] = act ? (pr * PSTR + pc) : (PROWS * PSTR + 4);  // spare slot
    }

    const float ph = h ? 0.f : 1.f;        // phantom v=7 killer (h=1,s=3)
    const int cbase = ti * PSTR + tj;      // pair addr of (pixel - (3,3))
    const int bh = cbase + h;              // base for the 4-per-row taps

    h2 Aacc[14];
    #pragma unroll
    for (int i = 0; i < 14; ++i) Aacc[i] = (h2){(__fp16)0.f, (__fp16)0.f};

    // balanced k-range: 3 chunks of 17, 5 of 16
    const int k0 = kc * 16 + (kc < 3 ? kc : 3);
    const int k1 = k0 + 16 + (kc < 3 ? 1 : 0);
    const float* fb = feats + (size_t)b * K_ * NN;

    // zero-init BOTH LDS buffers once: pad cols 22,23 / spare slot stay 0
    for (int e = tid; e < 2 * LDSP; e += 256)
        (&patch2[0][0])[e] = make_float2(0.f, 0.f);

    // prefetch k0 (pre = f * mask * log2e)
    const float* fk0 = fb + (size_t)k0 * NN;
    float pr0 = fk0[soff[0]] * swt[0];
    float pr1 = fk0[soff[1]] * swt[1];

    __syncthreads();   // zero-init visible before anyone stages

    // stage k0 into buffer 0; prefetch raw k0+1 (chunks are >= 16 long)
    patch2[0][slds[0]] = make_float2(ozw[0] * exp2f(pr0), ozw[0] * exp2f(-pr0));
    patch2[0][slds[1]] = make_float2(ozw[1] * exp2f(pr1), ozw[1] * exp2f(-pr1));
    {
        const float* fn = fb + (size_t)(k0 + 1) * NN;
        pr0 = fn[soff[0]] * swt[0];
        pr1 = fn[soff[1]] * swt[1];
    }
    __syncthreads();   // buf0 ready

    int p = 0;
    for (int k = k0; k < k1; ++k) {
        const float cpk = cp[k];
        const float2* buf = patch2[p];
        const float c0 = pr0, c1 = pr1;    // raw*swt for k+1 (if any)
        if (k + 2 < k1) {                  // issue k+2 loads before taps
            const float* fn = fb + (size_t)(k + 2) * NN;
            pr0 = fn[soff[0]] * swt[0];
            pr1 = fn[soff[1]] * swt[1];
        }

        // ---- tap phase: register-pipelined LDS loads (1-row lookahead) ----
        const float2 cpair = buf[cbase + R_ * PSTR + R_];
        h2 ex[14];
        float dsum = 0.f;
        float2 n0 = buf[bh];
        float2 n1 = buf[bh + 2];
        float2 n2 = buf[bh + 4];
        float2 n3 = buf[bh + 6];
        #pragma unroll
        for (int u = 0; u < D_; ++u) {
            const float2 a0 = n0, a1 = n1, a2 = n2, a3 = n3;
            if (u < D_ - 1) {
                const int bn = bh + (u + 1) * PSTR;
                n0 = buf[bn];
                n1 = buf[bn + 2];
                n2 = buf[bn + 4];
                n3 = buf[bn + 6];
            }
            float t0 = fmaxf(cpair.x * a0.y, a0.x * cpair.y);
            float t1 = fmaxf(cpair.x * a1.y, a1.x * cpair.y);
            float t2 = fmaxf(cpair.x * a2.y, a2.x * cpair.y);
            float t3 = fmaxf(cpair.x * a3.y, a3.x * cpair.y);
            t3 *= ph;                      // kill phantom v=7 (reads REAL data)
            dsum += t0;
            dsum += t1;
            dsum += t2;
            dsum += t3;
            ex[u * 2]     = __builtin_amdgcn_cvt_pkrtz(t0, t1);
            ex[u * 2 + 1] = __builtin_amdgcn_cvt_pkrtz(t2, t3);
        }
        const float denom = dsum + __shfl_xor(dsum, 1, 64);  // lane pair = pixel
        const float scale = cpk * __frcp_rn(denom);          // denom >= 1
        const h2 s2 = __builtin_amdgcn_cvt_pkrtz(scale, scale);
        #pragma unroll
        for (int m = 0; m < 14; ++m) Aacc[m] = ex[m] * s2 + Aacc[m];

        if (k + 1 < k1) {                  // stage k+1 into alternate buffer
            float2* nb = patch2[p ^ 1];
            nb[slds[0]] = make_float2(ozw[0] * exp2f(c0), ozw[0] * exp2f(-c0));
            nb[slds[1]] = make_float2(ozw[1] * exp2f(c1), ozw[1] * exp2f(-c1));
        }
        __syncthreads();                   // ONE barrier per k
        p ^= 1;
    }

    if (mask[b * NN + gi * N_ + gj] != 0) {
        const int pixg = gi * N_ + gj;
        // w = u*7 + 2s + h; (t0,t1) -> offsets 0,2; (t2,t3) -> offsets 4,6
        float* ab = Aout + (size_t)b * W_ * NN + h * NN + pixg;
        #pragma unroll
        for (int u = 0; u < D_; ++u) {
            #pragma unroll
            for (int m = 0; m < 2; ++m) {
                const h2 tv = Aacc[u * 2 + m];
                atomicAdd(ab + (u * D_ + 4 * m) * NN, (float)tv[0]);
                if (h == 0 || m < 1)   // h=1,m=1 second tap = phantom v=7
                    atomicAdd(ab + (u * D_ + 4 * m + 2) * NN, (float)tv[1]);
            }
        }
    }
}

// Gather: out[b,q,c] = sum_w A[b,w,p]*x2[b,c,p], p=q-(u-3,v-3), w=u*7+v.
// Block = 64 q x 8 w-groups (512 thr); wg owns u=wg (wg=7 idle in taps).
// 21 c-accumulators in registers; LDS reduce over 8 planes; contiguous store.
#define RSTR 22   // LDS reduce stride
__global__ __launch_bounds__(512, 4) void rwn_gather(
    const float* __restrict__ Aarr,  // [B,W,NN]
    const float* __restrict__ x2,    // [B,C,NN]
    float* __restrict__ out)         // [B,NN,C]
{
    __shared__ float red[8 * 64 * RSTR];   // 45056 B

    const int q0 = blockIdx.x * 64;
    const int b  = blockIdx.y;
    const int tid = threadIdx.x;
    const int qh = tid & 63;         // lane -> consecutive q (coalesced)
    const int wg = tid >> 6;         // wave-uniform w-group = u
    const int q = q0 + qh;
    const int i = q >> 7, j = q & (N_ - 1);

    const float* Ab = Aarr + (size_t)b * W_ * NN;
    const float* xb = x2 + (size_t)b * C_ * NN;

    float acc[C_];
    #pragma unroll
    for (int c = 0; c < C_; ++c) acc[c] = 0.f;

    if (wg < D_) {
        const int pi = i - (wg - R_);
        const int cpi = pi < 0 ? 0 : (pi > N_ - 1 ? N_ - 1 : pi);
        const float rv = (pi >= 0 && pi < N_) ? 1.f : 0.f;
        const float* Aw = Ab + (size_t)wg * D_ * NN;
        #pragma unroll
        for (int v = 0; v < D_; ++v) {
            const int pj = j - (v - R_);
            const int cpj = pj < 0 ? 0 : (pj > N_ - 1 ? N_ - 1 : pj);
            const float vv = (pj >= 0 && pj < N_) ? rv : 0.f;
            const int p = cpi * N_ + cpj;
            const float a = vv * Aw[(size_t)v * NN + p];
            #pragma unroll
            for (int c = 0; c < C_; ++c)
                acc[c] += a * xb[(size_t)c * NN + p];
        }
    }

    // stage per-wg partials
    float* rbase = red + (wg * 64 + qh) * RSTR;
    #pragma unroll
    for (int c = 0; c < C_; ++c) rbase[c] = acc[c];
    __syncthreads();

    // reduce 8 planes, store contiguous (64*21 = 1344 floats)
    float* ob = out + ((size_t)b * NN + q0) * C_;
    for (int e = tid; e < 64 * C_; e += 512) {
        const int qq = e / C_, cc = e - qq * C_;
        const int a = qq * RSTR + cc;
        float s = 0.f;
        #pragma unroll
        for (int pl = 0; pl < 8; ++pl)
            s += red[pl * 64 * RSTR + a];
        ob[e] = s;
    }
}

extern "C" void kernel_launch(void* const* d_in, const int* in_sizes, int n_in,
                              void* d_out, int out_size, void* d_ws, size_t ws_size,
                              hipStream_t stream) {
    const float* feats = (const float*)d_in[0];   // [B,K,N,N]
    const float* x2    = (const float*)d_in[1];   // [B,C,NN]
    const int*   mask  = (const int*)d_in[2];     // [B,N,N]
    const float* cp    = (const float*)d_in[3];   // [K]
    float* out = (float*)d_out;

    float* Aarr = (float*)d_ws;                   // [B,W,NN] fp32
    const size_t Abytes = (size_t)B_ * W_ * NN * sizeof(float);

    (void)hipMemsetAsync(Aarr, 0, Abytes, stream);

    dim3 gridA(128, KC, B_);
    rwn_affinity<<<gridA, 256, 0, stream>>>(feats, mask, cp, Aarr);

    dim3 gridG(NN / 64, B_);
    rwn_gather<<<gridG, 512, 0, stream>>>(Aarr, x2, out);
}

// Round 3
// 154.242 us; speedup vs baseline: 1.4623x; 1.4623x over previous
//
#include <hip/hip_runtime.h>
#include <hip/hip_fp16.h>

#define R_ 3
#define D_ 7            // 2R+1
#define W_ 49
#define N_ 128
#define K_ 131
#define C_ 21
#define B_ 2
#define NN (N_ * N_)
#define TI_ 8                   // tile rows
#define TJ_ 16                  // tile cols
#define PROWS (TI_ + 2 * R_)    // 14
#define PCOLS (TJ_ + 2 * R_)    // 22
#define PSTR 24                 // LDS row stride (float2 pairs)
#define NELEM (PROWS * PCOLS)   // 308 staged elements
#define LDSP (PROWS * PSTR + 8) // 344 pairs (spare write slot at 340)
#define KC 8                    // k-chunks per tile
#define KCHUNK ((K_ + KC - 1) / KC)    // 17

typedef __fp16 h2 __attribute__((ext_vector_type(2)));

// Affinity: per-pixel 7x7 window softmax per channel, weighted by cp[k].
// exp(|c-n|) = max(Ec*EnInv, En*EcInv), (E,Einv) pairs staged per element
// (E = exp2(f*mask*log2e)). Lane pairs (2t,2t+1) share a pixel; h=tid&1 owns
// columns v=2s+h (s=0..3). The h=1,s=3 slot is the phantom v=7 tap: it reads
// a REAL staged element (column tj+7) for tj<15, so it MUST be killed
// explicitly with ph.
//
// R3 vs proven 73.7us R0 (structure/grid/numerics otherwise IDENTICAL;
// crucially NO launch_bounds register cap -- R2's cap caused scratch spill,
// visible as FETCH 30->240MB / WRITE 50->292MB):
//  * Tap loads hoisted into one fully-unrolled statically-indexed batch
//    (Ld[28]) issued before any consumption -> many ds_reads in flight,
//    one LDS-latency exposure per k instead of ~14.
//  * dsum as 4 parallel partials (chain 28 -> 7+2 adds). Reassociation
//    noise is far below the fp16 pack that dominates absmax.
__global__ __launch_bounds__(256) void rwn_affinity(
    const float* __restrict__ feats,   // [B,K,N,N]
    const int*   __restrict__ mask,    // [B,N,N]
    const float* __restrict__ cp,      // [K]
    float* __restrict__ Aout)          // [B,W,NN] (pre-zeroed)
{
    __shared__ float2 patch2[LDSP];

    const int tile = blockIdx.x;           // 0..127 (16x8 tiles of 8x16)
    const int kc   = blockIdx.y;
    const int b    = blockIdx.z;
    const int tr = tile >> 3, tc = tile & 7;
    const int ti0 = tr * TI_, tj0 = tc * TJ_;

    const int tid = threadIdx.x;
    const int pix = tid >> 1;              // 0..127
    const int h   = tid & 1;               // column-parity owner
    const int ti = pix >> 4;               // 0..7
    const int tj = pix & 15;               // 0..15
    const int gi = ti0 + ti, gj = tj0 + tj;

    // ---- hoisted staging setup: thread owns elements tid and 256+tid ----
    const float LOG2E = 1.4426950408889634f;
    int   soff[2];      // clamped global offset
    float swt[2];       // in-bounds * mask * log2e
    float ozw[2];       // 0 for OOB (store zero pair), 1 otherwise
    int   slds[2];      // pair index in LDS
    #pragma unroll
    for (int r = 0; r < 2; ++r) {
        int e = tid + r * 256;
        bool act = (e < NELEM);
        int pr = e / PCOLS, pc = e - pr * PCOLS;
        int mi = ti0 + pr - R_, mj = tj0 + pc - R_;
        bool inb = act && mi >= 0 && mi < N_ && mj >= 0 && mj < N_;
        int cmi = mi < 0 ? 0 : (mi > N_ - 1 ? N_ - 1 : mi);
        int cmj = mj < 0 ? 0 : (mj > N_ - 1 ? N_ - 1 : mj);
        soff[r] = cmi * N_ + cmj;
        swt[r]  = inb ? ((float)mask[b * NN + soff[r]] * LOG2E) : 0.f;
        ozw[r]  = inb ? 1.f : 0.f;
        slds[r] = act ? (pr * PSTR + pc) : (PROWS * PSTR + 4);  // spare slot
    }

    const float ph = h ? 0.f : 1.f;        // phantom v=7 killer (h=1,s=3)
    const int cbase = ti * PSTR + tj;      // pair addr of (pixel - (3,3))
    const int bh = cbase + h;              // single base for all 28 taps

    h2 Aacc[14];
    #pragma unroll
    for (int i = 0; i < 14; ++i) Aacc[i] = (h2){(__fp16)0.f, (__fp16)0.f};

    const int k0 = kc * KCHUNK;
    const int k1 = (k0 + KCHUNK < K_) ? (k0 + KCHUNK) : K_;
    const float* fb = feats + (size_t)b * K_ * NN;

    // zero-init all LDS pairs once: pad cols 22,23 / spare slot stay 0 forever
    for (int e = tid; e < LDSP; e += 256) patch2[e] = make_float2(0.f, 0.f);

    // software prefetch of first k (pre = f * mask * log2e)
    const float* fk0 = fb + (size_t)k0 * NN;
    float pre0 = fk0[soff[0]] * swt[0];
    float pre1 = fk0[soff[1]] * swt[1];

    __syncthreads();

    for (int k = k0; k < k1; ++k) {
        patch2[slds[0]] = make_float2(ozw[0] * exp2f(pre0), ozw[0] * exp2f(-pre0));
        patch2[slds[1]] = make_float2(ozw[1] * exp2f(pre1), ozw[1] * exp2f(-pre1));
        // prefetch next k while this one computes
        float n0 = 0.f, n1 = 0.f;
        if (k + 1 < k1) {
            const float* fn = fb + (size_t)(k + 1) * NN;
            n0 = fn[soff[0]] * swt[0];
            n1 = fn[soff[1]] * swt[1];
        }
        __syncthreads();

        // ---- tap phase: hoisted load batch, then pure-VALU compute ----
        const float2 cpair = patch2[cbase + R_ * PSTR + R_];
        float2 Ld[28];                       // statically indexed (full unroll)
        #pragma unroll
        for (int u = 0; u < D_; ++u) {
            const int bn = bh + u * PSTR;
            Ld[u * 4 + 0] = patch2[bn];
            Ld[u * 4 + 1] = patch2[bn + 2];
            Ld[u * 4 + 2] = patch2[bn + 4];
            Ld[u * 4 + 3] = patch2[bn + 6];
        }
        h2 ex[14];
        float d0 = 0.f, d1 = 0.f, d2 = 0.f, d3 = 0.f;
        #pragma unroll
        for (int u = 0; u < D_; ++u) {
            const float2 a0 = Ld[u * 4 + 0];
            const float2 a1 = Ld[u * 4 + 1];
            const float2 a2 = Ld[u * 4 + 2];
            const float2 a3 = Ld[u * 4 + 3];
            float t0 = fmaxf(cpair.x * a0.y, a0.x * cpair.y);
            float t1 = fmaxf(cpair.x * a1.y, a1.x * cpair.y);
            float t2 = fmaxf(cpair.x * a2.y, a2.x * cpair.y);
            float t3 = fmaxf(cpair.x * a3.y, a3.x * cpair.y) * ph; // phantom v=7
            d0 += t0;
            d1 += t1;
            d2 += t2;
            d3 += t3;
            ex[u * 2]     = __builtin_amdgcn_cvt_pkrtz(t0, t1);
            ex[u * 2 + 1] = __builtin_amdgcn_cvt_pkrtz(t2, t3);
        }
        const float dsum = (d0 + d1) + (d2 + d3);
        const float denom = dsum + __shfl_xor(dsum, 1, 64);  // lane pair = pixel
        const float scale = cp[k] * __frcp_rn(denom);        // denom >= 1
        const h2 s2 = __builtin_amdgcn_cvt_pkrtz(scale, scale);
        #pragma unroll
        for (int m = 0; m < 14; ++m) Aacc[m] = ex[m] * s2 + Aacc[m];
        __syncthreads();

        pre0 = n0; pre1 = n1;
    }

    if (mask[b * NN + gi * N_ + gj] != 0) {
        const int pixg = gi * N_ + gj;
        // w = u*7 + 2s + h; s=2m -> offset 4m; s=2m+1 -> offset 4m+2
        float* ab = Aout + (size_t)b * W_ * NN + h * NN + pixg;
        #pragma unroll
        for (int u = 0; u < D_; ++u) {
            #pragma unroll
            for (int m = 0; m < 2; ++m) {
                const h2 tv = Aacc[u * 2 + m];
                atomicAdd(ab + (u * D_ + 4 * m) * NN, (float)tv[0]);
                if (h == 0 || m < 1)   // h=1,m=1 second tap = phantom v=7
                    atomicAdd(ab + (u * D_ + 4 * m + 2) * NN, (float)tv[1]);
            }
        }
    }
}

// Gather: out[b,q,c] = sum_w A[b,w,p]*x2[b,c,p], p=q-(u-3,v-3), w=u*7+v.
// Block = 64 q x 8 w-groups (512 thr); wg owns u=wg (wg=7 idle in taps).
// 21 c-accumulators in registers; LDS reduce over 8 planes; contiguous store.
#define RSTR 22   // LDS reduce stride
__global__ __launch_bounds__(512, 4) void rwn_gather(
    const float* __restrict__ Aarr,  // [B,W,NN]
    const float* __restrict__ x2,    // [B,C,NN]
    float* __restrict__ out)         // [B,NN,C]
{
    __shared__ float red[8 * 64 * RSTR];   // 45056 B

    const int q0 = blockIdx.x * 64;
    const int b  = blockIdx.y;
    const int tid = threadIdx.x;
    const int qh = tid & 63;         // lane -> consecutive q (coalesced)
    const int wg = tid >> 6;         // wave-uniform w-group = u
    const int q = q0 + qh;
    const int i = q >> 7, j = q & (N_ - 1);

    const float* Ab = Aarr + (size_t)b * W_ * NN;
    const float* xb = x2 + (size_t)b * C_ * NN;

    float acc[C_];
    #pragma unroll
    for (int c = 0; c < C_; ++c) acc[c] = 0.f;

    if (wg < D_) {
        const int pi = i - (wg - R_);
        const int cpi = pi < 0 ? 0 : (pi > N_ - 1 ? N_ - 1 : pi);
        const float rv = (pi >= 0 && pi < N_) ? 1.f : 0.f;
        const float* Aw = Ab + (size_t)wg * D_ * NN;
        #pragma unroll
        for (int v = 0; v < D_; ++v) {
            const int pj = j - (v - R_);
            const int cpj = pj < 0 ? 0 : (pj > N_ - 1 ? N_ - 1 : pj);
            const float vv = (pj >= 0 && pj < N_) ? rv : 0.f;
            const int p = cpi * N_ + cpj;
            const float a = vv * Aw[(size_t)v * NN + p];
            #pragma unroll
            for (int c = 0; c < C_; ++c)
                acc[c] += a * xb[(size_t)c * NN + p];
        }
    }

    // stage per-wg partials
    float* rbase = red + (wg * 64 + qh) * RSTR;
    #pragma unroll
    for (int c = 0; c < C_; ++c) rbase[c] = acc[c];
    __syncthreads();

    // reduce 8 planes, store contiguous (64*21 = 1344 floats)
    float* ob = out + ((size_t)b * NN + q0) * C_;
    for (int e = tid; e < 64 * C_; e += 512) {
        const int qq = e / C_, cc = e - qq * C_;
        const int a = qq * RSTR + cc;
        float s = 0.f;
        #pragma unroll
        for (int pl = 0; pl < 8; ++pl)
            s += red[pl * 64 * RSTR + a];
        ob[e] = s;
    }
}

extern "C" void kernel_launch(void* const* d_in, const int* in_sizes, int n_in,
                              void* d_out, int out_size, void* d_ws, size_t ws_size,
                              hipStream_t stream) {
    const float* feats = (const float*)d_in[0];   // [B,K,N,N]
    const float* x2    = (const float*)d_in[1];   // [B,C,NN]
    const int*   mask  = (const int*)d_in[2];     // [B,N,N]
    const float* cp    = (const float*)d_in[3];   // [K]
    float* out = (float*)d_out;

    float* Aarr = (float*)d_ws;                   // [B,W,NN] fp32
    const size_t Abytes = (size_t)B_ * W_ * NN * sizeof(float);

    (void)hipMemsetAsync(Aarr, 0, Abytes, stream);

    dim3 gridA(128, KC, B_);
    rwn_affinity<<<gridA, 256, 0, stream>>>(feats, mask, cp, Aarr);

    dim3 gridG(NN / 64, B_);
    rwn_gather<<<gridG, 512, 0, stream>>>(Aarr, x2, out);
}

// Round 4
// 145.580 us; speedup vs baseline: 1.5493x; 1.0595x over previous
//
#include <hip/hip_runtime.h>
#include <hip/hip_fp16.h>

#define R_ 3
#define D_ 7            // 2R+1
#define W_ 49
#define N_ 128
#define K_ 131
#define C_ 21
#define B_ 2
#define NN (N_ * N_)
#define TI_ 8                   // tile rows
#define TJ_ 16                  // tile cols
#define PROWS (TI_ + 2 * R_)    // 14
#define PCOLS (TJ_ + 2 * R_)    // 22
#define PSTR 24                 // LDS row stride (float2 pairs)
#define NELEM (PROWS * PCOLS)   // 308 staged elements
#define LDSP (PROWS * PSTR + 8) // 344 pairs (spare write slot at 340)
#define KC 8                    // k-chunks per tile
#define KCHUNK ((K_ + KC - 1) / KC)    // 17
#define HCELLS (PROWS * PCOLS)  // 308 halo cells for gather

typedef __fp16 h2 __attribute__((ext_vector_type(2)));

// Affinity: EXACT R0 source (proven 73.7us; R1-R3 restructurings all lost).
// Per-pixel 7x7 window softmax per channel, weighted by cp[k].
// exp(|c-n|) = max(Ec*EnInv, En*EcInv), (E,Einv) pairs staged per element
// (E = exp2(f*mask*log2e)). Lane pairs (2t,2t+1) share a pixel; h=tid&1 owns
// columns v=2s+h (s=0..3). The h=1,s=3 slot is the phantom v=7 tap: it reads
// a REAL staged element (column tj+7) for tj<15, so it MUST be killed
// explicitly with ph.
__global__ __launch_bounds__(256) void rwn_affinity(
    const float* __restrict__ feats,   // [B,K,N,N]
    const int*   __restrict__ mask,    // [B,N,N]
    const float* __restrict__ cp,      // [K]
    float* __restrict__ Aout)          // [B,W,NN] (pre-zeroed)
{
    __shared__ float2 patch2[LDSP];

    const int tile = blockIdx.x;           // 0..127 (16x8 tiles of 8x16)
    const int kc   = blockIdx.y;
    const int b    = blockIdx.z;
    const int tr = tile >> 3, tc = tile & 7;
    const int ti0 = tr * TI_, tj0 = tc * TJ_;

    const int tid = threadIdx.x;
    const int pix = tid >> 1;              // 0..127
    const int h   = tid & 1;               // column-parity owner
    const int ti = pix >> 4;               // 0..7
    const int tj = pix & 15;               // 0..15
    const int gi = ti0 + ti, gj = tj0 + tj;

    // ---- hoisted staging setup: thread owns elements tid and 256+tid ----
    const float LOG2E = 1.4426950408889634f;
    int   soff[2];      // clamped global offset
    float swt[2];       // in-bounds * mask * log2e
    float ozw[2];       // 0 for OOB (store zero pair), 1 otherwise
    int   slds[2];      // pair index in LDS
    #pragma unroll
    for (int r = 0; r < 2; ++r) {
        int e = tid + r * 256;
        bool act = (e < NELEM);
        int pr = e / PCOLS, pc = e - pr * PCOLS;
        int mi = ti0 + pr - R_, mj = tj0 + pc - R_;
        bool inb = act && mi >= 0 && mi < N_ && mj >= 0 && mj < N_;
        int cmi = mi < 0 ? 0 : (mi > N_ - 1 ? N_ - 1 : mi);
        int cmj = mj < 0 ? 0 : (mj > N_ - 1 ? N_ - 1 : mj);
        soff[r] = cmi * N_ + cmj;
        swt[r]  = inb ? ((float)mask[b * NN + soff[r]] * LOG2E) : 0.f;
        ozw[r]  = inb ? 1.f : 0.f;
        slds[r] = act ? (pr * PSTR + pc) : (PROWS * PSTR + 4);  // spare slot
    }

    const float ph = h ? 0.f : 1.f;        // phantom v=7 killer (h=1,s=3)
    const int cbase = ti * PSTR + tj;      // pair addr of (pixel - (3,3))
    const int bh = cbase + h;              // single base for all 28 taps

    h2 Aacc[14];
    #pragma unroll
    for (int i = 0; i < 14; ++i) Aacc[i] = (h2){(__fp16)0.f, (__fp16)0.f};

    const int k0 = kc * KCHUNK;
    const int k1 = (k0 + KCHUNK < K_) ? (k0 + KCHUNK) : K_;
    const float* fb = feats + (size_t)b * K_ * NN;

    // zero-init all LDS pairs once: pad cols 22,23 / spare slot stay 0 forever
    for (int e = tid; e < LDSP; e += 256) patch2[e] = make_float2(0.f, 0.f);

    // software prefetch of first k (pre = f * mask * log2e)
    const float* fk0 = fb + (size_t)k0 * NN;
    float pre0 = fk0[soff[0]] * swt[0];
    float pre1 = fk0[soff[1]] * swt[1];

    __syncthreads();

    for (int k = k0; k < k1; ++k) {
        patch2[slds[0]] = make_float2(ozw[0] * exp2f(pre0), ozw[0] * exp2f(-pre0));
        patch2[slds[1]] = make_float2(ozw[1] * exp2f(pre1), ozw[1] * exp2f(-pre1));
        // prefetch next k while this one computes
        float n0 = 0.f, n1 = 0.f;
        if (k + 1 < k1) {
            const float* fn = fb + (size_t)(k + 1) * NN;
            n0 = fn[soff[0]] * swt[0];
            n1 = fn[soff[1]] * swt[1];
        }
        __syncthreads();

        const float2 cpair = patch2[cbase + R_ * PSTR + R_];
        h2 ex[14];
        float dsum = 0.f;
        #pragma unroll
        for (int u = 0; u < D_; ++u) {
            #pragma unroll
            for (int m = 0; m < 2; ++m) {
                // taps s=2m (t0) and s=2m+1 (t1); pair offsets 4m, 4m+2
                const float2 np0 = patch2[bh + u * PSTR + 4 * m];
                const float2 np1 = patch2[bh + u * PSTR + 4 * m + 2];
                float t0 = fmaxf(cpair.x * np0.y, np0.x * cpair.y);
                float t1 = fmaxf(cpair.x * np1.y, np1.x * cpair.y);
                if (m == 1) t1 *= ph;   // kill phantom v=7 (reads REAL data!)
                dsum += t0;
                dsum += t1;
                ex[u * 2 + m] = __builtin_amdgcn_cvt_pkrtz(t0, t1);
            }
        }
        const float denom = dsum + __shfl_xor(dsum, 1, 64);  // lane pair = pixel
        const float scale = cp[k] * __frcp_rn(denom);        // denom >= 1
        const h2 s2 = __builtin_amdgcn_cvt_pkrtz(scale, scale);
        #pragma unroll
        for (int m = 0; m < 14; ++m) Aacc[m] = ex[m] * s2 + Aacc[m];
        __syncthreads();

        pre0 = n0; pre1 = n1;
    }

    if (mask[b * NN + gi * N_ + gj] != 0) {
        const int pixg = gi * N_ + gj;
        // w = u*7 + 2s + h; s=2m -> offset 4m; s=2m+1 -> offset 4m+2
        float* ab = Aout + (size_t)b * W_ * NN + h * NN + pixg;
        #pragma unroll
        for (int u = 0; u < D_; ++u) {
            #pragma unroll
            for (int m = 0; m < 2; ++m) {
                const h2 tv = Aacc[u * 2 + m];
                atomicAdd(ab + (u * D_ + 4 * m) * NN, (float)tv[0]);
                if (h == 0 || m < 1)   // h=1,m=1 second tap = phantom v=7
                    atomicAdd(ab + (u * D_ + 4 * m + 2) * NN, (float)tv[1]);
            }
        }
    }
}

// Gather R4: tiled + LDS-staged. Block = one 8x16 q-tile (matches output
// partition, 256 blocks, 512 thr, 4 thr/q). Old version issued 49 A + 1029
// cached x2 loads per q plus a 45KB 8-plane LDS reduce; new version stages
// the 14x22 x2 halo x 21c ONCE in LDS (c-major, zero-filled OOB -> no
// validity math in the hot loop), reads A exactly once (coalesced), merges
// the 4 threads/q with a quad butterfly, and stores fully coalesced via a
// small LDS restage. No atomics, 3 barriers, f32-reassociation only.
__global__ __launch_bounds__(512) void rwn_gather(
    const float* __restrict__ Aarr,  // [B,W,NN]
    const float* __restrict__ x2,    // [B,C,NN]
    float* __restrict__ out)         // [B,NN,C]
{
    __shared__ float x2h[C_ * HCELLS];   // [c][cell], cell=pr*22+pc; 25.9KB

    const int tile = blockIdx.x;     // 0..127: 16 tile-rows x 8 tile-cols
    const int b    = blockIdx.y;
    const int tr = tile >> 3, tc = tile & 7;
    const int gi0 = tr * TI_, gj0 = tc * TJ_;

    const int tid = threadIdx.x;

    // ---- stage x2 halo (zero-filled OOB) ----
    const float* xb = x2 + (size_t)b * C_ * NN;
    for (int e = tid; e < C_ * HCELLS; e += 512) {
        const int c = e / HCELLS, cell = e - c * HCELLS;
        const int pr = cell / PCOLS, pc = cell - pr * PCOLS;
        const int mi = gi0 + pr - R_, mj = gj0 + pc - R_;
        const bool inb = (mi >= 0 && mi < N_ && mj >= 0 && mj < N_);
        const int cmi = mi < 0 ? 0 : (mi > N_ - 1 ? N_ - 1 : mi);
        const int cmj = mj < 0 ? 0 : (mj > N_ - 1 ? N_ - 1 : mj);
        x2h[e] = inb ? xb[c * NN + cmi * N_ + cmj] : 0.f;
    }
    __syncthreads();

    const int h = tid & 3;           // tap-group within quad
    const int q = tid >> 2;          // 0..127 local pixel
    const int qi = q >> 4, qj = q & 15;
    const int gi = gi0 + qi, gj = gj0 + qj;
    const float* Ab = Aarr + (size_t)b * W_ * NN;

    // ---- batch the ~13 A loads (one latency exposure) ----
    float av[13];
    int   cells[13];
    #pragma unroll
    for (int idx = 0; idx < 13; ++idx) {
        int w = h + 4 * idx;
        const float valid = (w < W_) ? 1.f : 0.f;
        if (w >= W_) w = W_ - 1;     // clamp for address safety
        const int u = w / D_, v = w - u * D_;
        const int pi = gi + R_ - u, pj = gj + R_ - v;
        const int cmi = pi < 0 ? 0 : (pi > N_ - 1 ? N_ - 1 : pi);
        const int cmj = pj < 0 ? 0 : (pj > N_ - 1 ? N_ - 1 : pj);
        av[idx]    = valid * Ab[(size_t)w * NN + cmi * N_ + cmj];
        cells[idx] = (qi + 2 * R_ - u) * PCOLS + (qj + 2 * R_ - v);
    }

    // ---- accumulate 21 channels (LDS reads: stride-1 across lanes) ----
    float acc[C_];
    #pragma unroll
    for (int c = 0; c < C_; ++c) acc[c] = 0.f;
    #pragma unroll
    for (int idx = 0; idx < 13; ++idx) {
        const float a = av[idx];
        const float* xc = x2h + cells[idx];
        #pragma unroll
        for (int c = 0; c < C_; ++c)
            acc[c] += a * xc[c * HCELLS];
    }

    // ---- quad butterfly merge ----
    #pragma unroll
    for (int c = 0; c < C_; ++c) {
        acc[c] += __shfl_xor(acc[c], 1, 64);
        acc[c] += __shfl_xor(acc[c], 2, 64);
    }

    // ---- restage to LDS, then fully coalesced store ----
    __syncthreads();                 // x2h dead; reuse as out staging
    if (h == 0) {
        float* os = x2h + q * C_;    // stride 21 words -> conflict-free
        #pragma unroll
        for (int c = 0; c < C_; ++c) os[c] = acc[c];
    }
    __syncthreads();
    for (int e = tid; e < TI_ * TJ_ * C_; e += 512) {
        const int qq = e / C_, cc = e - qq * C_;
        const int gq = (gi0 + (qq >> 4)) * N_ + gj0 + (qq & 15);
        out[((size_t)b * NN + gq) * C_ + cc] = x2h[e];
    }
}

extern "C" void kernel_launch(void* const* d_in, const int* in_sizes, int n_in,
                              void* d_out, int out_size, void* d_ws, size_t ws_size,
                              hipStream_t stream) {
    const float* feats = (const float*)d_in[0];   // [B,K,N,N]
    const float* x2    = (const float*)d_in[1];   // [B,C,NN]
    const int*   mask  = (const int*)d_in[2];     // [B,N,N]
    const float* cp    = (const float*)d_in[3];   // [K]
    float* out = (float*)d_out;

    float* Aarr = (float*)d_ws;                   // [B,W,NN] fp32
    const size_t Abytes = (size_t)B_ * W_ * NN * sizeof(float);

    (void)hipMemsetAsync(Aarr, 0, Abytes, stream);

    dim3 gridA(128, KC, B_);
    rwn_affinity<<<gridA, 256, 0, stream>>>(feats, mask, cp, Aarr);

    dim3 gridG(128, B_);
    rwn_gather<<<gridG, 512, 0, stream>>>(Aarr, x2, out);
}